// Round 1
// baseline (299.860 us; speedup 1.0000x reference)
//
#include <hip/hip_runtime.h>
#include <hip/hip_fp16.h>

typedef _Float16 half8 __attribute__((ext_vector_type(8)));
typedef float f32x4 __attribute__((ext_vector_type(4)));

#define BB 4
#define NB 8
#define LL 512
#define SS 512
#define HH 8
#define EE 64
#define ROWSTRIDE (HH * EE)   // 512 floats between consecutive l (or s) rows

// Block: 512 threads = 8 waves. Each block: one head (b,n,h) x 128 Q-rows.
// Wave w owns rows [w*16, w*16+16). Loop over S in tiles of 64.
// LDS: V^T (re,im) f16 for the whole head (swizzled) + per-wave P buffer.

__global__ __launch_bounds__(512) void cattn_kernel(
    const float* __restrict__ qre, const float* __restrict__ qim,
    const float* __restrict__ kre, const float* __restrict__ kim,
    const float* __restrict__ vre, const float* __restrict__ vim,
    float* __restrict__ out)
{
    __shared__ __align__(16) _Float16 VtRe[64 * 512];   // [d][s] swizzled, 64 KiB
    __shared__ __align__(16) _Float16 VtIm[64 * 512];   // 64 KiB
    __shared__ __align__(16) _Float16 Pbuf[8 * 16 * 64]; // per-wave [l][s] swizzled, 16 KiB

    const int tid  = threadIdx.x;
    const int wave = tid >> 6;
    const int lane = tid & 63;
    const int lgrp = lane >> 4;   // 0..3
    const int l16  = lane & 15;   // 0..15

    const int blk  = blockIdx.x;
    const int lt   = blk & 3;     // 4 L-tiles of 128
    const int head = blk >> 2;    // 0..255
    const int h    = head & 7;
    const int bn   = head >> 3;   // b*NB+n

    const size_t headQ = (size_t)bn * LL * ROWSTRIDE + (size_t)h * EE;
    const size_t headK = (size_t)bn * SS * ROWSTRIDE + (size_t)h * EE;

    // ---------------- stage V^T (f16, XOR-swizzled) ----------------
    for (int t = 0; t < 2; ++t) {
        const float* vsrc = t ? vim : vre;
        _Float16* vdst = t ? VtIm : VtRe;
        for (int it = 0; it < 2; ++it) {
            int idx = it * 512 + tid;          // 0..1023
            int d0  = (idx & 15) * 4;          // 0,4,..,60
            int s0  = (idx >> 4) * 8;          // 0,8,..,504
            float4 rv[8];
            #pragma unroll
            for (int i = 0; i < 8; ++i)
                rv[i] = *(const float4*)(vsrc + headK + (size_t)(s0 + i) * ROWSTRIDE + d0);
            #pragma unroll
            for (int dd = 0; dd < 4; ++dd) {
                int d = d0 + dd;
                half8 h8;
                #pragma unroll
                for (int i = 0; i < 8; ++i) h8[i] = (_Float16)((&rv[i].x)[dd]);
                int byteoff = d * 1024 + ((s0 * 2) ^ ((d & 7) << 4));
                *reinterpret_cast<half8*>(reinterpret_cast<char*>(vdst) + byteoff) = h8;
            }
        }
    }
    __syncthreads();   // only barrier in the kernel

    // ---------------- Q fragments (held in registers) ----------------
    // A-frag: lane holds q[l = l16][e = ec*32 + lgrp*8 + j]
    const int l0 = lt * 128 + wave * 16;
    half8 qr[2], qin[2];   // qr and -qi
    {
        size_t base = headQ + (size_t)(l0 + l16) * ROWSTRIDE + lgrp * 8;
        #pragma unroll
        for (int ec = 0; ec < 2; ++ec) {
            float4 a0 = *(const float4*)(qre + base + ec * 32);
            float4 a1 = *(const float4*)(qre + base + ec * 32 + 4);
            float4 b0 = *(const float4*)(qim + base + ec * 32);
            float4 b1 = *(const float4*)(qim + base + ec * 32 + 4);
            #pragma unroll
            for (int j = 0; j < 4; ++j) {
                qr[ec][j]     = (_Float16)((&a0.x)[j]);
                qr[ec][4 + j] = (_Float16)((&a1.x)[j]);
                qin[ec][j]     = (_Float16)(-(&b0.x)[j]);
                qin[ec][4 + j] = (_Float16)(-(&b1.x)[j]);
            }
        }
    }

    f32x4 ore[4], oim[4];
    #pragma unroll
    for (int n = 0; n < 4; ++n) { ore[n] = (f32x4){0.f,0.f,0.f,0.f}; oim[n] = (f32x4){0.f,0.f,0.f,0.f}; }
    float m[4], lsum[4];
    #pragma unroll
    for (int r = 0; r < 4; ++r) { m[r] = -1e30f; lsum[r] = 0.f; }

    _Float16* Pw = Pbuf + wave * 16 * 64;

    // ---------------- main loop over S tiles of 64 ----------------
    for (int st = 0; st < SS / 64; ++st) {
        // K fragments from global (L2-resident): B-frag lane holds k[s=n*16+l16][e=ec*32+lgrp*8+j]
        half8 krf[4][2], kif[4][2];
        #pragma unroll
        for (int n = 0; n < 4; ++n) {
            size_t base = headK + (size_t)(st * 64 + n * 16 + l16) * ROWSTRIDE + lgrp * 8;
            #pragma unroll
            for (int ec = 0; ec < 2; ++ec) {
                float4 a0 = *(const float4*)(kre + base + ec * 32);
                float4 a1 = *(const float4*)(kre + base + ec * 32 + 4);
                float4 b0 = *(const float4*)(kim + base + ec * 32);
                float4 b1 = *(const float4*)(kim + base + ec * 32 + 4);
                #pragma unroll
                for (int j = 0; j < 4; ++j) {
                    krf[n][ec][j]     = (_Float16)((&a0.x)[j]);
                    krf[n][ec][4 + j] = (_Float16)((&a1.x)[j]);
                    kif[n][ec][j]     = (_Float16)((&b0.x)[j]);
                    kif[n][ec][4 + j] = (_Float16)((&b1.x)[j]);
                }
            }
        }

        // scores: s_re = qr.kr + (-qi).ki ; s_im = qr.ki + (-qi).kr  (faithful signs)
        f32x4 sre[4], sim[4];
        #pragma unroll
        for (int n = 0; n < 4; ++n) {
            f32x4 z = (f32x4){0.f,0.f,0.f,0.f};
            z = __builtin_amdgcn_mfma_f32_16x16x32_f16(qr[0],  krf[n][0], z, 0, 0, 0);
            z = __builtin_amdgcn_mfma_f32_16x16x32_f16(qr[1],  krf[n][1], z, 0, 0, 0);
            z = __builtin_amdgcn_mfma_f32_16x16x32_f16(qin[0], kif[n][0], z, 0, 0, 0);
            z = __builtin_amdgcn_mfma_f32_16x16x32_f16(qin[1], kif[n][1], z, 0, 0, 0);
            sre[n] = z;
            f32x4 w = (f32x4){0.f,0.f,0.f,0.f};
            w = __builtin_amdgcn_mfma_f32_16x16x32_f16(qr[0],  kif[n][0], w, 0, 0, 0);
            w = __builtin_amdgcn_mfma_f32_16x16x32_f16(qr[1],  kif[n][1], w, 0, 0, 0);
            w = __builtin_amdgcn_mfma_f32_16x16x32_f16(qin[0], krf[n][0], w, 0, 0, 0);
            w = __builtin_amdgcn_mfma_f32_16x16x32_f16(qin[1], krf[n][1], w, 0, 0, 0);
            sim[n] = w;
        }

        // magnitude
        float mg[4][4];
        #pragma unroll
        for (int n = 0; n < 4; ++n)
            #pragma unroll
            for (int r = 0; r < 4; ++r)
                mg[n][r] = sqrtf(sre[n][r] * sre[n][r] + sim[n][r] * sim[n][r]);

        // online softmax (row l = lgrp*4 + r lives in the 16 lanes sharing lgrp)
        float pv[4][4];
        #pragma unroll
        for (int r = 0; r < 4; ++r) {
            float v = fmaxf(fmaxf(mg[0][r], mg[1][r]), fmaxf(mg[2][r], mg[3][r]));
            #pragma unroll
            for (int o = 1; o < 16; o <<= 1) v = fmaxf(v, __shfl_xor(v, o, 64));
            float mn = fmaxf(m[r], v);
            float sc = __expf(m[r] - mn);
            m[r] = mn;
            float ps = 0.f;
            #pragma unroll
            for (int n = 0; n < 4; ++n) {
                float p = __expf(mg[n][r] - mn);
                pv[n][r] = p;
                ps += p;
            }
            #pragma unroll
            for (int o = 1; o < 16; o <<= 1) ps += __shfl_xor(ps, o, 64);
            lsum[r] = lsum[r] * sc + ps;
            #pragma unroll
            for (int n = 0; n < 4; ++n) { ore[n][r] *= sc; oim[n][r] *= sc; }
        }

        // write P (f16, swizzled): row l = lgrp*4+r, col s = n*16+l16
        #pragma unroll
        for (int r = 0; r < 4; ++r) {
            int l = lgrp * 4 + r;
            int rowoff = l * 128;
            int swz = (l & 7) << 4;
            #pragma unroll
            for (int n = 0; n < 4; ++n) {
                int col = (n * 16 + l16) * 2;
                *reinterpret_cast<_Float16*>(reinterpret_cast<char*>(Pw) + rowoff + (col ^ swz)) =
                    (_Float16)pv[n][r];
            }
        }

        // PV: O[l][d] += P[l][s] * V[s][d]
        #pragma unroll
        for (int kc = 0; kc < 2; ++kc) {
            int prow = l16 * 128;
            int pcol = (kc * 32 + lgrp * 8) * 2;
            half8 pa = *reinterpret_cast<half8*>(reinterpret_cast<char*>(Pw) + prow + (pcol ^ ((l16 & 7) << 4)));
            int sbase = st * 64 + kc * 32 + lgrp * 8;
            #pragma unroll
            for (int n = 0; n < 4; ++n) {
                int d = n * 16 + l16;
                int voff = d * 1024 + ((sbase * 2) ^ ((d & 7) << 4));
                half8 vbr = *reinterpret_cast<half8*>(reinterpret_cast<char*>(VtRe) + voff);
                half8 vbi = *reinterpret_cast<half8*>(reinterpret_cast<char*>(VtIm) + voff);
                ore[n] = __builtin_amdgcn_mfma_f32_16x16x32_f16(pa, vbr, ore[n], 0, 0, 0);
                oim[n] = __builtin_amdgcn_mfma_f32_16x16x32_f16(pa, vbi, oim[n], 0, 0, 0);
            }
        }
    }

    // ---------------- epilogue ----------------
    const size_t outImOff = (size_t)BB * NB * LL * HH * EE;
    #pragma unroll
    for (int r = 0; r < 4; ++r) {
        int l = l0 + lgrp * 4 + r;
        float inv = 1.f / lsum[r];
        size_t obase = ((size_t)bn * LL + l) * ROWSTRIDE + (size_t)h * EE;
        #pragma unroll
        for (int n = 0; n < 4; ++n) {
            int d = n * 16 + l16;
            out[obase + d]            = ore[n][r] * inv;
            out[outImOff + obase + d] = oim[n][r] * inv;
        }
    }
}

extern "C" void kernel_launch(void* const* d_in, const int* in_sizes, int n_in,
                              void* d_out, int out_size, void* d_ws, size_t ws_size,
                              hipStream_t stream) {
    const float* qre = (const float*)d_in[0];
    const float* qim = (const float*)d_in[1];
    const float* kre = (const float*)d_in[2];
    const float* kim = (const float*)d_in[3];
    const float* vre = (const float*)d_in[4];
    const float* vim = (const float*)d_in[5];
    float* out = (float*)d_out;
    dim3 grid(1024), block(512);
    hipLaunchKernelGGL(cattn_kernel, grid, block, 0, stream,
                       qre, qim, kre, kim, vre, vim, out);
}

// Round 3
// 109.673 us; speedup vs baseline: 2.7341x; 2.7341x over previous
//
#include <hip/hip_runtime.h>
#include <hip/hip_fp16.h>

typedef _Float16 half8 __attribute__((ext_vector_type(8)));
typedef _Float16 half4 __attribute__((ext_vector_type(4)));
typedef __fp16  fp16x2 __attribute__((ext_vector_type(2)));
typedef float f32x4 __attribute__((ext_vector_type(4)));

#define BB 4
#define NB 8
#define LL 512
#define SS 512
#define HH 8
#define EE 64
#define ROWSTRIDE (HH * EE)   // 512 floats between consecutive l (or s) rows

// Block: 512 threads = 8 waves; one (head, 128-row L-tile) per block.
// Per S-tile of 64: K and V^T staged in double-buffered swizzled f16 LDS.
// Swapped QK^T (A=K, B=Q) -> lane owns one query row l = lane&15:
//   scalar online-softmax state, in-register P redistribution via shfl.

__global__ __launch_bounds__(512, 4) void cattn_kernel(
    const float* __restrict__ qre, const float* __restrict__ qim,
    const float* __restrict__ kre, const float* __restrict__ kim,
    const float* __restrict__ vre, const float* __restrict__ vim,
    float* __restrict__ out)
{
    // 64 KiB total LDS -> 2 blocks/CU
    __shared__ __align__(16) _Float16 KtRe[2][64 * 64];  // [buf][s][e] swizzled
    __shared__ __align__(16) _Float16 KtIm[2][64 * 64];
    __shared__ __align__(16) _Float16 VtRe[2][64 * 64];  // [buf][d][s] swizzled
    __shared__ __align__(16) _Float16 VtIm[2][64 * 64];

    const int tid  = threadIdx.x;
    const int wave = tid >> 6;
    const int lane = tid & 63;
    const int lgrp = lane >> 4;   // 0..3
    const int l16  = lane & 15;   // 0..15

    // bijective XCD swizzle: nwg=1024, 8 XCDs, 128 blocks per XCD chunk
    const int bid  = blockIdx.x;
    const int nid  = (bid & 7) * 128 + (bid >> 3);
    const int lt   = nid & 3;     // L-tile (128 rows)
    const int head = nid >> 2;    // 0..255
    const int h    = head & 7;
    const int bn   = head >> 3;

    const size_t headQ = (size_t)bn * LL * ROWSTRIDE + (size_t)h * EE;
    const size_t headK = (size_t)bn * SS * ROWSTRIDE + (size_t)h * EE;

    // ---------------- staging (K row-major, V transposed; both f16 swizzled) ----
    auto stage = [&](int st, int buf) {
        const int tb = st * 64;
        // K: 2 arrays x 64 rows x 8 e-chunks = 1024 items
        #pragma unroll
        for (int it = 0; it < 2; ++it) {
            int idx = it * 512 + tid;
            int ec  = idx & 7;            // e0 = ec*8
            int s   = (idx >> 3) & 63;
            int arr = idx >> 9;
            const float* src = arr ? kim : kre;
            const float* p = src + headK + (size_t)(tb + s) * ROWSTRIDE + ec * 8;
            float4 a = *(const float4*)p;
            float4 b = *(const float4*)(p + 4);
            half8 hv;
            #pragma unroll
            for (int j = 0; j < 4; ++j) {
                hv[j]     = (_Float16)((&a.x)[j]);
                hv[4 + j] = (_Float16)((&b.x)[j]);
            }
            _Float16* base = arr ? KtIm[buf] : KtRe[buf];
            *reinterpret_cast<half8*>(reinterpret_cast<char*>(base) +
                s * 128 + ((ec * 16) ^ ((s & 7) << 4))) = hv;
        }
        // V transpose: 2 arrays x 16 d-groups x 16 s-groups = 512 items
        {
            int arr = tid >> 8;
            int d0  = (tid & 15) * 4;
            int s0  = ((tid >> 4) & 15) * 4;
            const float* src = arr ? vim : vre;
            float4 rv[4];
            #pragma unroll
            for (int i = 0; i < 4; ++i)
                rv[i] = *(const float4*)(src + headK + (size_t)(tb + s0 + i) * ROWSTRIDE + d0);
            _Float16* base = arr ? VtIm[buf] : VtRe[buf];
            #pragma unroll
            for (int dd = 0; dd < 4; ++dd) {
                int d = d0 + dd;
                half4 hv;
                #pragma unroll
                for (int i = 0; i < 4; ++i) hv[i] = (_Float16)((&rv[i].x)[dd]);
                *reinterpret_cast<half4*>(reinterpret_cast<char*>(base) +
                    d * 128 + ((s0 * 2) ^ ((d & 7) << 4))) = hv;
            }
        }
    };

    // ---------------- Q fragments (B-operand: lane holds Q[l=l16][e=lgrp*8+j]) --
    const int l0 = lt * 128 + wave * 16;
    half8 qr[2], qin[2];   // qr and -qi
    {
        size_t base = headQ + (size_t)(l0 + l16) * ROWSTRIDE + lgrp * 8;
        #pragma unroll
        for (int ec = 0; ec < 2; ++ec) {
            float4 a0 = *(const float4*)(qre + base + ec * 32);
            float4 a1 = *(const float4*)(qre + base + ec * 32 + 4);
            float4 b0 = *(const float4*)(qim + base + ec * 32);
            float4 b1 = *(const float4*)(qim + base + ec * 32 + 4);
            #pragma unroll
            for (int j = 0; j < 4; ++j) {
                qr[ec][j]      = (_Float16)((&a0.x)[j]);
                qr[ec][4 + j]  = (_Float16)((&a1.x)[j]);
                qin[ec][j]     = (_Float16)(-(&b0.x)[j]);
                qin[ec][4 + j] = (_Float16)(-(&b1.x)[j]);
            }
        }
    }

    f32x4 ore[4], oim[4];
    #pragma unroll
    for (int n = 0; n < 4; ++n) { ore[n] = (f32x4){0.f,0.f,0.f,0.f}; oim[n] = (f32x4){0.f,0.f,0.f,0.f}; }
    float m = -1e30f, lsum = 0.f;

    stage(0, 0);
    __syncthreads();

    const int srcA = l16 + ((lane & 16) << 1);  // lgrp_src = 2*(lgrp&1)
    const int srcB = srcA + 16;
    const bool hi  = lane >= 32;                // selects upper n-tile pair

    // ---------------- main loop over 8 S-tiles ----------------
    for (int st = 0; st < 8; ++st) {
        const int cur = st & 1;
        if (st < 7) stage(st + 1, cur ^ 1);

        const char* KR = (const char*)KtRe[cur];
        const char* KI = (const char*)KtIm[cur];
        const char* VR = (const char*)VtRe[cur];
        const char* VI = (const char*)VtIm[cur];

        // scores^T: lane holds mag[s = n*16 + lgrp*4 + r][l = l16]
        float p_[4][4];
        float tmax = 0.f;
        #pragma unroll
        for (int n = 0; n < 4; ++n) {
            int srow = n * 16 + l16;
            int rb   = srow * 128;
            int swz  = (srow & 7) << 4;
            half8 kr0 = *(const half8*)(KR + rb + ((lgrp * 16)      ^ swz));
            half8 kr1 = *(const half8*)(KR + rb + ((64 + lgrp * 16) ^ swz));
            half8 ki0 = *(const half8*)(KI + rb + ((lgrp * 16)      ^ swz));
            half8 ki1 = *(const half8*)(KI + rb + ((64 + lgrp * 16) ^ swz));
            f32x4 z = (f32x4){0.f,0.f,0.f,0.f};
            z = __builtin_amdgcn_mfma_f32_16x16x32_f16(kr0, qr[0],  z, 0, 0, 0);
            z = __builtin_amdgcn_mfma_f32_16x16x32_f16(kr1, qr[1],  z, 0, 0, 0);
            z = __builtin_amdgcn_mfma_f32_16x16x32_f16(ki0, qin[0], z, 0, 0, 0);
            z = __builtin_amdgcn_mfma_f32_16x16x32_f16(ki1, qin[1], z, 0, 0, 0);
            f32x4 w = (f32x4){0.f,0.f,0.f,0.f};
            w = __builtin_amdgcn_mfma_f32_16x16x32_f16(ki0, qr[0],  w, 0, 0, 0);
            w = __builtin_amdgcn_mfma_f32_16x16x32_f16(ki1, qr[1],  w, 0, 0, 0);
            w = __builtin_amdgcn_mfma_f32_16x16x32_f16(kr0, qin[0], w, 0, 0, 0);
            w = __builtin_amdgcn_mfma_f32_16x16x32_f16(kr1, qin[1], w, 0, 0, 0);
            #pragma unroll
            for (int r = 0; r < 4; ++r) {
                float mg = sqrtf(z[r] * z[r] + w[r] * w[r]);
                p_[n][r] = mg;
                tmax = fmaxf(tmax, mg);
            }
        }

        // online softmax, one row per lane (4-way replicated across lgrps)
        tmax = fmaxf(tmax, __shfl_xor(tmax, 16));
        tmax = fmaxf(tmax, __shfl_xor(tmax, 32));
        float mn = fmaxf(m, tmax);
        float sc = __expf(m - mn);
        m = mn;
        float ps = 0.f;
        #pragma unroll
        for (int n = 0; n < 4; ++n)
            #pragma unroll
            for (int r = 0; r < 4; ++r) {
                float pe = __expf(p_[n][r] - mn);
                p_[n][r] = pe;
                ps += pe;
            }
        ps += __shfl_xor(ps, 16);
        ps += __shfl_xor(ps, 32);
        lsum = lsum * sc + ps;
        float scr[4];
        #pragma unroll
        for (int r = 0; r < 4; ++r) scr[r] = __shfl(sc, lgrp * 4 + r);
        #pragma unroll
        for (int n = 0; n < 4; ++n)
            #pragma unroll
            for (int r = 0; r < 4; ++r) { ore[n][r] *= scr[r]; oim[n][r] *= scr[r]; }

        // pack P to f16 pairs: pku[n][t] = {P[l16][n*16+lgrp*4+2t], +2t+1}
        unsigned int pku[4][2];
        #pragma unroll
        for (int n = 0; n < 4; ++n)
            #pragma unroll
            for (int t = 0; t < 2; ++t) {
                union { fp16x2 h; unsigned int u; } cv;
                cv.h = __builtin_amdgcn_cvt_pkrtz(p_[n][2 * t], p_[n][2 * t + 1]);
                pku[n][t] = cv.u;
            }

        // PV: redistribute P to A-frag via shfl, then mfma against V^T from LDS
        #pragma unroll
        for (int kc = 0; kc < 2; ++kc) {
            union { half8 h; unsigned int u[4]; } pa;
            unsigned int xA0 = __shfl(pku[2 * kc][0],     srcA);
            unsigned int xB0 = __shfl(pku[2 * kc + 1][0], srcA);
            unsigned int xA1 = __shfl(pku[2 * kc][1],     srcA);
            unsigned int xB1 = __shfl(pku[2 * kc + 1][1], srcA);
            unsigned int xA2 = __shfl(pku[2 * kc][0],     srcB);
            unsigned int xB2 = __shfl(pku[2 * kc + 1][0], srcB);
            unsigned int xA3 = __shfl(pku[2 * kc][1],     srcB);
            unsigned int xB3 = __shfl(pku[2 * kc + 1][1], srcB);
            pa.u[0] = hi ? xB0 : xA0;
            pa.u[1] = hi ? xB1 : xA1;
            pa.u[2] = hi ? xB2 : xA2;
            pa.u[3] = hi ? xB3 : xA3;

            int sb2 = (kc * 32 + lgrp * 8) * 2;
            #pragma unroll
            for (int nd = 0; nd < 4; ++nd) {
                int d  = nd * 16 + l16;
                int vo = d * 128 + (sb2 ^ ((d & 7) << 4));
                half8 vr = *(const half8*)(VR + vo);
                half8 vi = *(const half8*)(VI + vo);
                ore[nd] = __builtin_amdgcn_mfma_f32_16x16x32_f16(pa.h, vr, ore[nd], 0, 0, 0);
                oim[nd] = __builtin_amdgcn_mfma_f32_16x16x32_f16(pa.h, vi, oim[nd], 0, 0, 0);
            }
        }

        __syncthreads();
    }

    // ---------------- epilogue: O[l = lgrp*4+r][d = nd*16+l16] ----------------
    const size_t outImOff = (size_t)BB * NB * LL * HH * EE;
    #pragma unroll
    for (int r = 0; r < 4; ++r) {
        int lrow = l0 + lgrp * 4 + r;
        float ls  = __shfl(lsum, lgrp * 4 + r);
        float inv = 1.f / ls;
        size_t obase = ((size_t)bn * LL + lrow) * ROWSTRIDE + (size_t)h * EE;
        #pragma unroll
        for (int nd = 0; nd < 4; ++nd) {
            int d = nd * 16 + l16;
            out[obase + d]            = ore[nd][r] * inv;
            out[outImOff + obase + d] = oim[nd][r] * inv;
        }
    }
}

extern "C" void kernel_launch(void* const* d_in, const int* in_sizes, int n_in,
                              void* d_out, int out_size, void* d_ws, size_t ws_size,
                              hipStream_t stream) {
    const float* qre = (const float*)d_in[0];
    const float* qim = (const float*)d_in[1];
    const float* kre = (const float*)d_in[2];
    const float* kim = (const float*)d_in[3];
    const float* vre = (const float*)d_in[4];
    const float* vim = (const float*)d_in[5];
    float* out = (float*)d_out;
    dim3 grid(1024), block(512);
    hipLaunchKernelGGL(cattn_kernel, grid, block, 0, stream,
                       qre, qim, kre, kim, vre, vim, out);
}

// Round 4
// 104.981 us; speedup vs baseline: 2.8563x; 1.0447x over previous
//
#include <hip/hip_runtime.h>
#include <hip/hip_fp16.h>

typedef _Float16 half8 __attribute__((ext_vector_type(8)));
typedef _Float16 half4 __attribute__((ext_vector_type(4)));
typedef __fp16  fp16x2 __attribute__((ext_vector_type(2)));
typedef float f32x4 __attribute__((ext_vector_type(4)));

#define BB 4
#define NB 8
#define LL 512
#define SS 512
#define HH 8
#define EE 64
#define ROWSTRIDE (HH * EE)   // 512 floats between consecutive l (or s) rows

// Block: 512 threads = 8 waves; one (head, 128-row L-tile) per block.
// Per S-tile of 64: K and V^T in double-buffered swizzled f16 LDS.
// T14 async split: global->reg loads issued BEFORE compute, cvt+LDS-write after.
// Swapped QK^T (A=K, B=Q): lane owns query row l = lane&15; scalar softmax state.

__global__ __launch_bounds__(512, 4) void cattn_kernel(
    const float* __restrict__ qre, const float* __restrict__ qim,
    const float* __restrict__ kre, const float* __restrict__ kim,
    const float* __restrict__ vre, const float* __restrict__ vim,
    float* __restrict__ out)
{
    // 64 KiB total LDS -> 2 blocks/CU
    __shared__ __align__(16) _Float16 KtRe[2][64 * 64];  // [buf][s][e] swizzled
    __shared__ __align__(16) _Float16 KtIm[2][64 * 64];
    __shared__ __align__(16) _Float16 VtRe[2][64 * 64];  // [buf][d][s] swizzled
    __shared__ __align__(16) _Float16 VtIm[2][64 * 64];

    const int tid  = threadIdx.x;
    const int wave = tid >> 6;
    const int lane = tid & 63;
    const int lgrp = lane >> 4;   // 0..3
    const int l16  = lane & 15;   // 0..15

    // bijective XCD swizzle: nwg=1024, 8 XCDs, 128 blocks per XCD chunk
    const int bid  = blockIdx.x;
    const int nid  = (bid & 7) * 128 + (bid >> 3);
    const int lt   = nid & 3;     // L-tile (128 rows)
    const int head = nid >> 2;    // 0..255
    const int h    = head & 7;
    const int bn   = head >> 3;

    const size_t headQ = (size_t)bn * LL * ROWSTRIDE + (size_t)h * EE;
    const size_t headK = (size_t)bn * SS * ROWSTRIDE + (size_t)h * EE;

    // staging registers (T14: load-early / write-late)
    float4 ka[2], kb[2];   // K: 2 items x 8 f32
    float4 vv[4];          // V: 4 s-rows x 4 d-cols

    // per-thread staging geometry (compile-time-ish, reused by load and write)
    const int kEc0  = tid & 7;               // it=0 e-chunk
    const int kS0   = (tid >> 3) & 63;       // it=0 s-row
    const int kArr0 = 0;                     // it=0: tid<512 -> idx<512 -> kre
    const int kEc1  = kEc0;                  // it=1: idx=512+tid -> same ec/s, arr=1
    const int kS1   = kS0;
    const int vArr  = tid >> 8;
    const int vD0   = (tid & 15) * 4;
    const int vS0   = ((tid >> 4) & 15) * 4;

    auto stage_load = [&](int st) {
        const int tb = st * 64;
        {
            const float* p = kre + headK + (size_t)(tb + kS0) * ROWSTRIDE + kEc0 * 8;
            ka[0] = *(const float4*)p;
            kb[0] = *(const float4*)(p + 4);
        }
        {
            const float* p = kim + headK + (size_t)(tb + kS1) * ROWSTRIDE + kEc1 * 8;
            ka[1] = *(const float4*)p;
            kb[1] = *(const float4*)(p + 4);
        }
        {
            const float* src = vArr ? vim : vre;
            #pragma unroll
            for (int i = 0; i < 4; ++i)
                vv[i] = *(const float4*)(src + headK + (size_t)(tb + vS0 + i) * ROWSTRIDE + vD0);
        }
    };

    auto stage_write = [&](int buf) {
        #pragma unroll
        for (int it = 0; it < 2; ++it) {
            half8 hv;
            #pragma unroll
            for (int j = 0; j < 4; ++j) {
                hv[j]     = (_Float16)((&ka[it].x)[j]);
                hv[4 + j] = (_Float16)((&kb[it].x)[j]);
            }
            _Float16* base = it ? KtIm[buf] : KtRe[buf];
            *reinterpret_cast<half8*>(reinterpret_cast<char*>(base) +
                kS0 * 128 + ((kEc0 * 16) ^ ((kS0 & 7) << 4))) = hv;
        }
        {
            _Float16* base = vArr ? VtIm[buf] : VtRe[buf];
            #pragma unroll
            for (int dd = 0; dd < 4; ++dd) {
                int d = vD0 + dd;
                half4 hv;
                #pragma unroll
                for (int i = 0; i < 4; ++i) hv[i] = (_Float16)((&vv[i].x)[dd]);
                *reinterpret_cast<half4*>(reinterpret_cast<char*>(base) +
                    d * 128 + ((vS0 * 2) ^ ((d & 7) << 4))) = hv;
            }
        }
    };

    // ---------------- Q fragments (B-operand: lane holds Q[l=l16][e=lgrp*8+j]) --
    const int l0 = lt * 128 + wave * 16;
    half8 qr[2], qin[2];   // qr and -qi
    {
        size_t base = headQ + (size_t)(l0 + l16) * ROWSTRIDE + lgrp * 8;
        #pragma unroll
        for (int ec = 0; ec < 2; ++ec) {
            float4 a0 = *(const float4*)(qre + base + ec * 32);
            float4 a1 = *(const float4*)(qre + base + ec * 32 + 4);
            float4 b0 = *(const float4*)(qim + base + ec * 32);
            float4 b1 = *(const float4*)(qim + base + ec * 32 + 4);
            #pragma unroll
            for (int j = 0; j < 4; ++j) {
                qr[ec][j]      = (_Float16)((&a0.x)[j]);
                qr[ec][4 + j]  = (_Float16)((&a1.x)[j]);
                qin[ec][j]     = (_Float16)(-(&b0.x)[j]);
                qin[ec][4 + j] = (_Float16)(-(&b1.x)[j]);
            }
        }
    }

    f32x4 ore[4], oim[4];
    #pragma unroll
    for (int n = 0; n < 4; ++n) { ore[n] = (f32x4){0.f,0.f,0.f,0.f}; oim[n] = (f32x4){0.f,0.f,0.f,0.f}; }
    float m = -1e30f, lsum = 0.f;

    stage_load(0);
    stage_write(0);
    __syncthreads();

    const int srcA = l16 + ((lane & 16) << 1);  // lgrp_src = 2*(lgrp&1)
    const int srcB = srcA + 16;
    const bool hi  = lane >= 32;                // selects upper n-tile pair

    // ---------------- main loop over 8 S-tiles ----------------
    for (int st = 0; st < 8; ++st) {
        const int cur = st & 1;
        if (st < 7) stage_load(st + 1);   // loads in flight during compute

        const char* KR = (const char*)KtRe[cur];
        const char* KI = (const char*)KtIm[cur];
        const char* VR = (const char*)VtRe[cur];
        const char* VI = (const char*)VtIm[cur];

        // scores^T: lane holds mag[s = n*16 + lgrp*4 + r][l = l16]
        float p_[4][4];
        float tmax = 0.f;
        #pragma unroll
        for (int n = 0; n < 4; ++n) {
            int srow = n * 16 + l16;
            int rb   = srow * 128;
            int swz  = (srow & 7) << 4;
            half8 kr0 = *(const half8*)(KR + rb + ((lgrp * 16)      ^ swz));
            half8 kr1 = *(const half8*)(KR + rb + ((64 + lgrp * 16) ^ swz));
            half8 ki0 = *(const half8*)(KI + rb + ((lgrp * 16)      ^ swz));
            half8 ki1 = *(const half8*)(KI + rb + ((64 + lgrp * 16) ^ swz));
            f32x4 z = (f32x4){0.f,0.f,0.f,0.f};
            z = __builtin_amdgcn_mfma_f32_16x16x32_f16(kr0, qr[0],  z, 0, 0, 0);
            z = __builtin_amdgcn_mfma_f32_16x16x32_f16(kr1, qr[1],  z, 0, 0, 0);
            z = __builtin_amdgcn_mfma_f32_16x16x32_f16(ki0, qin[0], z, 0, 0, 0);
            z = __builtin_amdgcn_mfma_f32_16x16x32_f16(ki1, qin[1], z, 0, 0, 0);
            f32x4 w = (f32x4){0.f,0.f,0.f,0.f};
            w = __builtin_amdgcn_mfma_f32_16x16x32_f16(ki0, qr[0],  w, 0, 0, 0);
            w = __builtin_amdgcn_mfma_f32_16x16x32_f16(ki1, qr[1],  w, 0, 0, 0);
            w = __builtin_amdgcn_mfma_f32_16x16x32_f16(kr0, qin[0], w, 0, 0, 0);
            w = __builtin_amdgcn_mfma_f32_16x16x32_f16(kr1, qin[1], w, 0, 0, 0);
            #pragma unroll
            for (int r = 0; r < 4; ++r) {
                float mg = sqrtf(z[r] * z[r] + w[r] * w[r]);
                p_[n][r] = mg;
                tmax = fmaxf(tmax, mg);
            }
        }

        // online softmax, one row per lane (4-way replicated across lgrps)
        tmax = fmaxf(tmax, __shfl_xor(tmax, 16));
        tmax = fmaxf(tmax, __shfl_xor(tmax, 32));
        float mn = fmaxf(m, tmax);
        // exact defer: if no row's max grew, sc == exp(0) == 1 -> skip rescale
        if (__any(tmax > m)) {
            float sc = __expf(m - mn);
            lsum *= sc;
            float scr[4];
            #pragma unroll
            for (int r = 0; r < 4; ++r) scr[r] = __shfl(sc, lgrp * 4 + r);
            #pragma unroll
            for (int n = 0; n < 4; ++n)
                #pragma unroll
                for (int r = 0; r < 4; ++r) { ore[n][r] *= scr[r]; oim[n][r] *= scr[r]; }
        }
        m = mn;
        float ps = 0.f;
        #pragma unroll
        for (int n = 0; n < 4; ++n)
            #pragma unroll
            for (int r = 0; r < 4; ++r) {
                float pe = __expf(p_[n][r] - mn);
                p_[n][r] = pe;
                ps += pe;
            }
        ps += __shfl_xor(ps, 16);
        ps += __shfl_xor(ps, 32);
        lsum += ps;

        // pack P to f16 pairs: pku[n][t] = {P[l16][n*16+lgrp*4+2t], +2t+1}
        unsigned int pku[4][2];
        #pragma unroll
        for (int n = 0; n < 4; ++n)
            #pragma unroll
            for (int t = 0; t < 2; ++t) {
                union { fp16x2 h; unsigned int u; } cv;
                cv.h = __builtin_amdgcn_cvt_pkrtz(p_[n][2 * t], p_[n][2 * t + 1]);
                pku[n][t] = cv.u;
            }

        // PV: redistribute P to A-frag via shfl, then mfma against V^T from LDS
        #pragma unroll
        for (int kc = 0; kc < 2; ++kc) {
            union { half8 h; unsigned int u[4]; } pa;
            unsigned int xA0 = __shfl(pku[2 * kc][0],     srcA);
            unsigned int xB0 = __shfl(pku[2 * kc + 1][0], srcA);
            unsigned int xA1 = __shfl(pku[2 * kc][1],     srcA);
            unsigned int xB1 = __shfl(pku[2 * kc + 1][1], srcA);
            unsigned int xA2 = __shfl(pku[2 * kc][0],     srcB);
            unsigned int xB2 = __shfl(pku[2 * kc + 1][0], srcB);
            unsigned int xA3 = __shfl(pku[2 * kc][1],     srcB);
            unsigned int xB3 = __shfl(pku[2 * kc + 1][1], srcB);
            pa.u[0] = hi ? xB0 : xA0;
            pa.u[1] = hi ? xB1 : xA1;
            pa.u[2] = hi ? xB2 : xA2;
            pa.u[3] = hi ? xB3 : xA3;

            int sb2 = (kc * 32 + lgrp * 8) * 2;
            #pragma unroll
            for (int nd = 0; nd < 4; ++nd) {
                int d  = nd * 16 + l16;
                int vo = d * 128 + (sb2 ^ ((d & 7) << 4));
                half8 vr = *(const half8*)(VR + vo);
                half8 vi = *(const half8*)(VI + vo);
                ore[nd] = __builtin_amdgcn_mfma_f32_16x16x32_f16(pa.h, vr, ore[nd], 0, 0, 0);
                oim[nd] = __builtin_amdgcn_mfma_f32_16x16x32_f16(pa.h, vi, oim[nd], 0, 0, 0);
            }
        }

        if (st < 7) stage_write(cur ^ 1);  // convert + LDS write AFTER compute
        __syncthreads();
    }

    // ---------------- epilogue: O[l = lgrp*4+r][d = nd*16+l16] ----------------
    const size_t outImOff = (size_t)BB * NB * LL * HH * EE;
    #pragma unroll
    for (int r = 0; r < 4; ++r) {
        int lrow = l0 + lgrp * 4 + r;
        float ls  = __shfl(lsum, lgrp * 4 + r);
        float inv = 1.f / ls;
        size_t obase = ((size_t)bn * LL + lrow) * ROWSTRIDE + (size_t)h * EE;
        #pragma unroll
        for (int nd = 0; nd < 4; ++nd) {
            int d = nd * 16 + l16;
            out[obase + d]            = ore[nd][r] * inv;
            out[outImOff + obase + d] = oim[nd][r] * inv;
        }
    }
}

extern "C" void kernel_launch(void* const* d_in, const int* in_sizes, int n_in,
                              void* d_out, int out_size, void* d_ws, size_t ws_size,
                              hipStream_t stream) {
    const float* qre = (const float*)d_in[0];
    const float* qim = (const float*)d_in[1];
    const float* kre = (const float*)d_in[2];
    const float* kim = (const float*)d_in[3];
    const float* vre = (const float*)d_in[4];
    const float* vim = (const float*)d_in[5];
    float* out = (float*)d_out;
    dim3 grid(1024), block(512);
    hipLaunchKernelGGL(cattn_kernel, grid, block, 0, stream,
                       qre, qim, kre, kim, vre, vim, out);
}

// Round 5
// 82.363 us; speedup vs baseline: 3.6407x; 1.2746x over previous
//
#include <hip/hip_runtime.h>
#include <hip/hip_fp16.h>

typedef _Float16 half8 __attribute__((ext_vector_type(8)));
typedef _Float16 half4 __attribute__((ext_vector_type(4)));
typedef __fp16  fp16x2 __attribute__((ext_vector_type(2)));
typedef float f32x4 __attribute__((ext_vector_type(4)));

#define BB 4
#define NB 8
#define LL 512
#define SS 512
#define HH 8
#define EE 64
#define ROWSTRIDE (HH * EE)   // 512 floats between consecutive l (or s) rows

__device__ __forceinline__ unsigned pkh(float a, float b) {
    union { fp16x2 h; unsigned u; } c;
    c.h = __builtin_amdgcn_cvt_pkrtz(a, b);
    return c.u;
}

// Block: 512 threads = 8 waves; one (head, 128-row L-tile) per block.
// Per S-tile of 64: K and V^T in double-buffered swizzled f16 LDS.
// T14 async split: global->reg loads issued BEFORE compute, cvt+LDS-write after.
// Swapped QK^T (A=K, B=Q): lane owns query row l = lane&15; scalar softmax state.
// P goes through a per-wave swizzled LDS tile (2-way banks) instead of bpermute.

__global__ __launch_bounds__(512, 4) void cattn_kernel(
    const float* __restrict__ qre, const float* __restrict__ qim,
    const float* __restrict__ kre, const float* __restrict__ kim,
    const float* __restrict__ vre, const float* __restrict__ vim,
    float* __restrict__ out)
{
    // 80 KiB total LDS -> 2 blocks/CU
    __shared__ __align__(16) _Float16 KtRe[2][64 * 64];  // [buf][s][e] swizzled
    __shared__ __align__(16) _Float16 KtIm[2][64 * 64];
    __shared__ __align__(16) _Float16 VtRe[2][64 * 64];  // [buf][d][s] swizzled
    __shared__ __align__(16) _Float16 VtIm[2][64 * 64];
    __shared__ __align__(16) _Float16 Pbuf[8][16 * 64];  // per-wave P[l][s] swizzled

    const int tid  = threadIdx.x;
    const int wave = tid >> 6;
    const int lane = tid & 63;
    const int lgrp = lane >> 4;   // 0..3
    const int l16  = lane & 15;   // 0..15

    // bijective XCD swizzle: nwg=1024, 8 XCDs, 128 blocks per XCD chunk
    const int bid  = blockIdx.x;
    const int nid  = (bid & 7) * 128 + (bid >> 3);
    const int lt   = nid & 3;     // L-tile (128 rows)
    const int head = nid >> 2;    // 0..255
    const int h    = head & 7;
    const int bn   = head >> 3;

    const size_t headQ = (size_t)bn * LL * ROWSTRIDE + (size_t)h * EE;
    const size_t headK = (size_t)bn * SS * ROWSTRIDE + (size_t)h * EE;

    // staging registers (T14: load-early / write-late)
    float4 ka[2], kb[2];   // K: 2 items x 8 f32
    float4 vv[4];          // V: 4 s-rows x 4 d-cols

    const int kEc0  = tid & 7;               // e-chunk
    const int kS0   = (tid >> 3) & 63;       // s-row
    const int vArr  = tid >> 8;
    const int vD0   = (tid & 15) * 4;
    const int vS0   = ((tid >> 4) & 15) * 4;

    auto stage_load = [&](int st) {
        const int tb = st * 64;
        {
            const float* p = kre + headK + (size_t)(tb + kS0) * ROWSTRIDE + kEc0 * 8;
            ka[0] = *(const float4*)p;
            kb[0] = *(const float4*)(p + 4);
        }
        {
            const float* p = kim + headK + (size_t)(tb + kS0) * ROWSTRIDE + kEc0 * 8;
            ka[1] = *(const float4*)p;
            kb[1] = *(const float4*)(p + 4);
        }
        {
            const float* src = vArr ? vim : vre;
            #pragma unroll
            for (int i = 0; i < 4; ++i)
                vv[i] = *(const float4*)(src + headK + (size_t)(tb + vS0 + i) * ROWSTRIDE + vD0);
        }
    };

    auto stage_write = [&](int buf) {
        #pragma unroll
        for (int it = 0; it < 2; ++it) {
            union { half8 h; unsigned u[4]; } kv;
            kv.u[0] = pkh(ka[it].x, ka[it].y);
            kv.u[1] = pkh(ka[it].z, ka[it].w);
            kv.u[2] = pkh(kb[it].x, kb[it].y);
            kv.u[3] = pkh(kb[it].z, kb[it].w);
            _Float16* base = it ? KtIm[buf] : KtRe[buf];
            *reinterpret_cast<half8*>(reinterpret_cast<char*>(base) +
                kS0 * 128 + ((kEc0 * 16) ^ ((kS0 & 7) << 4))) = kv.h;
        }
        {
            _Float16* base = vArr ? VtIm[buf] : VtRe[buf];
            #pragma unroll
            for (int dd = 0; dd < 4; ++dd) {
                int d = vD0 + dd;
                union { half4 h; unsigned u[2]; } hv;
                hv.u[0] = pkh((&vv[0].x)[dd], (&vv[1].x)[dd]);
                hv.u[1] = pkh((&vv[2].x)[dd], (&vv[3].x)[dd]);
                *reinterpret_cast<half4*>(reinterpret_cast<char*>(base) +
                    d * 128 + ((vS0 * 2) ^ ((d & 7) << 4))) = hv.h;
            }
        }
    };

    // ---------------- Q fragments (B-operand: lane holds Q[l=l16][e=lgrp*8+j]) --
    const int l0 = lt * 128 + wave * 16;
    half8 qr[2], qin[2];   // qr and -qi
    {
        size_t base = headQ + (size_t)(l0 + l16) * ROWSTRIDE + lgrp * 8;
        #pragma unroll
        for (int ec = 0; ec < 2; ++ec) {
            float4 a0 = *(const float4*)(qre + base + ec * 32);
            float4 a1 = *(const float4*)(qre + base + ec * 32 + 4);
            float4 b0 = *(const float4*)(qim + base + ec * 32);
            float4 b1 = *(const float4*)(qim + base + ec * 32 + 4);
            #pragma unroll
            for (int j = 0; j < 4; ++j) {
                qr[ec][j]      = (_Float16)((&a0.x)[j]);
                qr[ec][4 + j]  = (_Float16)((&a1.x)[j]);
                qin[ec][j]     = (_Float16)(-(&b0.x)[j]);
                qin[ec][4 + j] = (_Float16)(-(&b1.x)[j]);
            }
        }
    }

    f32x4 ore[4], oim[4];
    #pragma unroll
    for (int n = 0; n < 4; ++n) { ore[n] = (f32x4){0.f,0.f,0.f,0.f}; oim[n] = (f32x4){0.f,0.f,0.f,0.f}; }
    float m = -1e30f, lsum = 0.f;

    stage_load(0);
    stage_write(0);
    __syncthreads();

    char* Pw = reinterpret_cast<char*>(&Pbuf[wave][0]);
    const int prow = l16 * 128;
    const int pswz = (l16 & 7) << 4;

    // ---------------- main loop over 8 S-tiles ----------------
    for (int st = 0; st < 8; ++st) {
        const int cur = st & 1;
        if (st < 7) stage_load(st + 1);   // loads in flight during compute

        const char* KR = (const char*)KtRe[cur];
        const char* KI = (const char*)KtIm[cur];
        const char* VR = (const char*)VtRe[cur];
        const char* VI = (const char*)VtIm[cur];

        // scores^T: lane holds mag[s = n*16 + lgrp*4 + r][l = l16]
        float p_[4][4];
        float tmax = 0.f;
        #pragma unroll
        for (int n = 0; n < 4; ++n) {
            int srow = n * 16 + l16;
            int rb   = srow * 128;
            int swz  = (srow & 7) << 4;
            half8 kr0 = *(const half8*)(KR + rb + ((lgrp * 16)      ^ swz));
            half8 kr1 = *(const half8*)(KR + rb + ((64 + lgrp * 16) ^ swz));
            half8 ki0 = *(const half8*)(KI + rb + ((lgrp * 16)      ^ swz));
            half8 ki1 = *(const half8*)(KI + rb + ((64 + lgrp * 16) ^ swz));
            f32x4 z = (f32x4){0.f,0.f,0.f,0.f};
            z = __builtin_amdgcn_mfma_f32_16x16x32_f16(kr0, qr[0],  z, 0, 0, 0);
            z = __builtin_amdgcn_mfma_f32_16x16x32_f16(kr1, qr[1],  z, 0, 0, 0);
            z = __builtin_amdgcn_mfma_f32_16x16x32_f16(ki0, qin[0], z, 0, 0, 0);
            z = __builtin_amdgcn_mfma_f32_16x16x32_f16(ki1, qin[1], z, 0, 0, 0);
            f32x4 w = (f32x4){0.f,0.f,0.f,0.f};
            w = __builtin_amdgcn_mfma_f32_16x16x32_f16(ki0, qr[0],  w, 0, 0, 0);
            w = __builtin_amdgcn_mfma_f32_16x16x32_f16(ki1, qr[1],  w, 0, 0, 0);
            w = __builtin_amdgcn_mfma_f32_16x16x32_f16(kr0, qin[0], w, 0, 0, 0);
            w = __builtin_amdgcn_mfma_f32_16x16x32_f16(kr1, qin[1], w, 0, 0, 0);
            #pragma unroll
            for (int r = 0; r < 4; ++r) {
                float mg = __builtin_amdgcn_sqrtf(z[r] * z[r] + w[r] * w[r]);
                p_[n][r] = mg;
                tmax = fmaxf(tmax, mg);
            }
        }

        // online softmax, one row per lane (4-way replicated across lgrps)
        tmax = fmaxf(tmax, __shfl_xor(tmax, 16));
        tmax = fmaxf(tmax, __shfl_xor(tmax, 32));
        float mn = fmaxf(m, tmax);
        // exact defer: if no row's max grew, sc == exp(0) == 1 -> skip rescale
        if (__any(tmax > m)) {
            float sc = __expf(m - mn);
            lsum *= sc;
            float scr[4];
            #pragma unroll
            for (int r = 0; r < 4; ++r) scr[r] = __shfl(sc, lgrp * 4 + r);
            #pragma unroll
            for (int n = 0; n < 4; ++n)
                #pragma unroll
                for (int r = 0; r < 4; ++r) { ore[n][r] *= scr[r]; oim[n][r] *= scr[r]; }
        }
        m = mn;
        float ps = 0.f;
        #pragma unroll
        for (int n = 0; n < 4; ++n)
            #pragma unroll
            for (int r = 0; r < 4; ++r) {
                float pe = __expf(p_[n][r] - mn);
                p_[n][r] = pe;
                ps += pe;
            }
        ps += __shfl_xor(ps, 16);
        ps += __shfl_xor(ps, 32);
        lsum += ps;

        // write P rows to per-wave LDS: row l16, s-run n*16+lgrp*4..+3 (8B each)
        #pragma unroll
        for (int n = 0; n < 4; ++n) {
            uint2 val;
            val.x = pkh(p_[n][0], p_[n][1]);
            val.y = pkh(p_[n][2], p_[n][3]);
            *reinterpret_cast<uint2*>(Pw + prow + ((n * 32 + lgrp * 8) ^ pswz)) = val;
        }

        // PV: read A-frag P[l16][kc*32+lgrp*8 ..+7] from LDS, mfma against V^T
        #pragma unroll
        for (int kc = 0; kc < 2; ++kc) {
            half8 pa = *reinterpret_cast<const half8*>(Pw + prow + ((kc * 64 + lgrp * 16) ^ pswz));
            int sb2 = (kc * 32 + lgrp * 8) * 2;
            #pragma unroll
            for (int nd = 0; nd < 4; ++nd) {
                int d  = nd * 16 + l16;
                int vo = d * 128 + (sb2 ^ ((d & 7) << 4));
                half8 vr = *(const half8*)(VR + vo);
                half8 vi = *(const half8*)(VI + vo);
                ore[nd] = __builtin_amdgcn_mfma_f32_16x16x32_f16(pa, vr, ore[nd], 0, 0, 0);
                oim[nd] = __builtin_amdgcn_mfma_f32_16x16x32_f16(pa, vi, oim[nd], 0, 0, 0);
            }
        }

        if (st < 7) stage_write(cur ^ 1);  // convert + LDS write AFTER compute
        __syncthreads();
    }

    // ---------------- epilogue: O[l = lgrp*4+r][d = nd*16+l16] ----------------
    const size_t outImOff = (size_t)BB * NB * LL * HH * EE;
    #pragma unroll
    for (int r = 0; r < 4; ++r) {
        int lrow = l0 + lgrp * 4 + r;
        float ls  = __shfl(lsum, lgrp * 4 + r);
        float inv = 1.f / ls;
        size_t obase = ((size_t)bn * LL + lrow) * ROWSTRIDE + (size_t)h * EE;
        #pragma unroll
        for (int nd = 0; nd < 4; ++nd) {
            int d = nd * 16 + l16;
            out[obase + d]            = ore[nd][r] * inv;
            out[outImOff + obase + d] = oim[nd][r] * inv;
        }
    }
}

extern "C" void kernel_launch(void* const* d_in, const int* in_sizes, int n_in,
                              void* d_out, int out_size, void* d_ws, size_t ws_size,
                              hipStream_t stream) {
    const float* qre = (const float*)d_in[0];
    const float* qim = (const float*)d_in[1];
    const float* kre = (const float*)d_in[2];
    const float* kim = (const float*)d_in[3];
    const float* vre = (const float*)d_in[4];
    const float* vim = (const float*)d_in[5];
    float* out = (float*)d_out;
    dim3 grid(1024), block(512);
    hipLaunchKernelGGL(cattn_kernel, grid, block, 0, stream,
                       qre, qim, kre, kim, vre, vim, out);
}